// Round 4
// baseline (75.141 us; speedup 1.0000x reference)
//
#include <hip/hip_runtime.h>

#define B_ROWS 8192
#define IN_DIM 512
#define OUT_DIM 512
#define NDEG 8                 // DEGREE+1
#define KDIM (IN_DIM * NDEG)   // 4096
#define ZSLICES 4
#define NKT 16                 // K-steps (of 64) per z-slice
#define BM 256
#define BN 128
#define LDB 72                 // padded B LDS stride (shorts)

typedef short bf16x8 __attribute__((ext_vector_type(8)));
typedef float f32x4  __attribute__((ext_vector_type(4)));

__device__ __forceinline__ unsigned short f2bf(float f) {
  unsigned u = __float_as_uint(f);
  u += 0x7fffu + ((u >> 16) & 1u);   // RNE
  return (unsigned short)(u >> 16);
}

__device__ __forceinline__ void laguerre8(float t, float* L) {
  L[0] = 1.0f;
  L[1] = 1.5f - t;
#pragma unroll
  for (int k = 2; k < NDEG; ++k)
    L[k] = ((2.0f * (float)k - 0.5f - t) * L[k - 1] -
            ((float)k - 0.5f) * L[k - 2]) * (1.0f / (float)k);
  }

// ---- pass 1 (merged): basis -> A (tile-major pre-swizzled) | coeffs -> Bt ------
// A chunk(16B) index = (mtile*64 + ktile)*2048 + r*8 + (c ^ (r&7));  r=b%256, c=i%8
__global__ void prep_kernel(const float* __restrict__ x, const float* __restrict__ cf,
                            unsigned short* __restrict__ A, unsigned short* __restrict__ Bt) {
  int g = blockIdx.x;
  if (g < (B_ROWS * IN_DIM) / 256) {
    int idx = g * 256 + threadIdx.x;
    int b = idx >> 9, i = idx & 511;
    float L[NDEG];
    laguerre8(tanhf(x[idx]), L);
    uint4 v;
    v.x = (unsigned)f2bf(L[0]) | ((unsigned)f2bf(L[1]) << 16);
    v.y = (unsigned)f2bf(L[2]) | ((unsigned)f2bf(L[3]) << 16);
    v.z = (unsigned)f2bf(L[4]) | ((unsigned)f2bf(L[5]) << 16);
    v.w = (unsigned)f2bf(L[6]) | ((unsigned)f2bf(L[7]) << 16);
    int T = b >> 8, r = b & 255, kt = i >> 3, c = i & 7;
    size_t chunk = ((size_t)(T * 64 + kt)) * 2048 + r * 8 + (c ^ (r & 7));
    ((uint4*)A)[chunk] = v;
  } else {
    int idx = (g - (B_ROWS * IN_DIM) / 256) * 256 + threadIdx.x;   // i*512 + o
    int i = idx >> 9, o = idx & 511;
    const float4* cp = (const float4*)(cf + (size_t)idx * 8);
    float4 c0 = cp[0], c1 = cp[1];
    uint4 v;
    v.x = (unsigned)f2bf(c0.x) | ((unsigned)f2bf(c0.y) << 16);
    v.y = (unsigned)f2bf(c0.z) | ((unsigned)f2bf(c0.w) << 16);
    v.z = (unsigned)f2bf(c1.x) | ((unsigned)f2bf(c1.y) << 16);
    v.w = (unsigned)f2bf(c1.z) | ((unsigned)f2bf(c1.w) << 16);
    ((uint4*)Bt)[o * 512 + i] = v;
  }
}

// ---- pass 2: GEMM, 2-phase double-buffered pipeline -----------------------------
// A: global_load_lds (pre-swizzled source -> linear LDS), B: reg-staged padded LDS.
// Stage(t+1) issued BEFORE compute(t); one barrier per K-step.
__global__ __launch_bounds__(512, 2) void gemm_kernel(const unsigned short* __restrict__ A,
                                                      const unsigned short* __restrict__ Bt,
                                                      unsigned short* __restrict__ P) {
  __shared__ unsigned short lds[51200];   // 100 KB: As0/As1 16384 each, Bs0/Bs1 9216 each

  const int tid = threadIdx.x;
  const int lane = tid & 63;
  const int w = tid >> 6;
  const int wm = w >> 1, wn = w & 1;     // 4m x 2n waves, wave-tile 64x64

  // XCD-aware decode (512 blocks): xcd owns (z, y-half)
  const int g = blockIdx.x;
  const int xcd = g & 7, idx = g >> 3;
  const int z = xcd >> 1;
  const int y = (xcd & 1) * 16 + (idx & 15);   // m-tile 0..31
  const int bn = (idx >> 4) * BN;

  const uint4* Ag = (const uint4*)A;
  const uint4* Bg = (const uint4*)Bt;
  const size_t tile0 = ((size_t)(y * 64 + z * NKT)) * 2048;

  const int rB = tid >> 2, cB = (tid & 3) * 2;   // B staging coords

  // fragment addressing (byte-level done in shorts)
  const int arow = lane & 15, hi = lane >> 4;
  const int swz0 = hi ^ (arow & 7);
  const int aoff0 = (wm * 64 + arow) * 64 + swz0 * 8;
  const int aoff1 = (wm * 64 + arow) * 64 + (swz0 ^ 4) * 8;
  const int boff  = (wn * 64 + arow) * LDB;

  f32x4 zero = {0.f, 0.f, 0.f, 0.f};
  f32x4 acc[4][4];
#pragma unroll
  for (int mi = 0; mi < 4; ++mi)
#pragma unroll
    for (int ni = 0; ni < 4; ++ni) acc[mi][ni] = zero;

  // ---- prologue: stage tile 0 into buffer 0 ----
  uint4 rb0 = Bg[(size_t)(bn + rB) * 512 + z * NKT * 8 + cB];
  uint4 rb1 = Bg[(size_t)(bn + rB) * 512 + z * NKT * 8 + cB + 1];
  {
    size_t base = tile0 + w * 256;
    unsigned short* dst = lds + w * 2048;
#pragma unroll
    for (int j = 0; j < 4; ++j)
      __builtin_amdgcn_global_load_lds(
          (const __attribute__((address_space(1))) unsigned int*)(Ag + base + j * 64 + lane),
          (__attribute__((address_space(3))) unsigned int*)(dst + j * 512), 16, 0, 0);
  }
  *(uint4*)&lds[32768 + rB * LDB + cB * 8] = rb0;
  *(uint4*)&lds[32768 + rB * LDB + (cB + 1) * 8] = rb1;
  __syncthreads();

  // ---- main loop: compute buf[kt&1], stage kt+1 into buf[(kt+1)&1] ----
#pragma unroll 2
  for (int kt = 0; kt < NKT; ++kt) {
    const int cur = kt & 1, nb = cur ^ 1;
    if (kt + 1 < NKT) {
      rb0 = Bg[(size_t)(bn + rB) * 512 + (z * NKT + kt + 1) * 8 + cB];
      rb1 = Bg[(size_t)(bn + rB) * 512 + (z * NKT + kt + 1) * 8 + cB + 1];
      size_t base = tile0 + (size_t)(kt + 1) * 2048 + w * 256;
      unsigned short* dst = lds + nb * 16384 + w * 2048;
#pragma unroll
      for (int j = 0; j < 4; ++j)
        __builtin_amdgcn_global_load_lds(
            (const __attribute__((address_space(1))) unsigned int*)(Ag + base + (size_t)(kt + 1) * 0 + base - base + j * 64 + lane),
            (__attribute__((address_space(3))) unsigned int*)(dst + j * 512), 16, 0, 0);
      __builtin_amdgcn_sched_barrier(0);   // pin stage-issue before compute
    }

    const unsigned short* Ac = lds + cur * 16384;
    const unsigned short* Bc = lds + 32768 + cur * 9216;
    bf16x8 af0[4], af1[4], bf0[4], bf1[4];
#pragma unroll
    for (int mi = 0; mi < 4; ++mi) {
      af0[mi] = *(const bf16x8*)(Ac + aoff0 + mi * 1024);
      af1[mi] = *(const bf16x8*)(Ac + aoff1 + mi * 1024);
    }
#pragma unroll
    for (int ni = 0; ni < 4; ++ni) {
      bf0[ni] = *(const bf16x8*)(Bc + boff + ni * 16 * LDB + hi * 8);
      bf1[ni] = *(const bf16x8*)(Bc + boff + ni * 16 * LDB + 32 + hi * 8);
    }
    __builtin_amdgcn_s_setprio(1);
#pragma unroll
    for (int mi = 0; mi < 4; ++mi)
#pragma unroll
      for (int ni = 0; ni < 4; ++ni)
        acc[mi][ni] = __builtin_amdgcn_mfma_f32_16x16x32_bf16(af0[mi], bf0[ni], acc[mi][ni], 0, 0, 0);
#pragma unroll
    for (int mi = 0; mi < 4; ++mi)
#pragma unroll
      for (int ni = 0; ni < 4; ++ni)
        acc[mi][ni] = __builtin_amdgcn_mfma_f32_16x16x32_bf16(af1[mi], bf1[ni], acc[mi][ni], 0, 0, 0);
    __builtin_amdgcn_s_setprio(0);

    if (kt + 1 < NKT) {   // B(t+1) regs -> other buffer (compiler waits vmcnt for rb)
      unsigned short* BsN = lds + 32768 + nb * 9216;
      *(uint4*)&BsN[rB * LDB + cB * 8] = rb0;
      *(uint4*)&BsN[rB * LDB + (cB + 1) * 8] = rb1;
    }
    __syncthreads();   // drains A(t+1) gl_lds + B writes; next tile ready
  }

  // ---- epilogue: bf16 via per-wave LDS bounce -> full-line uint4 stores ----
  unsigned short* W = lds + w * 4096;    // reuse A region after final barrier
#pragma unroll
  for (int mi = 0; mi < 4; ++mi)
#pragma unroll
    for (int ni = 0; ni < 4; ++ni) {
      int col = ni * 16 + arow;
      int c8 = col >> 3, cpos = col & 7;
#pragma unroll
      for (int r = 0; r < 4; ++r) {
        int row = mi * 16 + hi * 4 + r;
        W[row * 64 + ((c8 ^ (row & 7)) << 3) + cpos] = f2bf(acc[mi][ni][r]);
      }
    }
  const int rr = lane >> 3, cc = lane & 7;
#pragma unroll
  for (int it = 0; it < 8; ++it) {
    int row = it * 8 + rr;
    uint4 v = *(uint4*)&W[row * 64 + ((cc ^ (row & 7)) << 3)];
    size_t pr = ((size_t)z * B_ROWS + (y * 256 + wm * 64 + row)) * 512 + bn + wn * 64 + cc * 8;
    *(uint4*)&P[pr] = v;
  }
}

// ---- pass 3: out = sum of bf16 partials, f32 ------------------------------------
__global__ void reduce_kernel(const unsigned short* __restrict__ P, float* __restrict__ out) {
  size_t t = (size_t)blockIdx.x * 256 + threadIdx.x;
  const uint4* p = (const uint4*)P;
  const size_t stride = (size_t)B_ROWS * OUT_DIM / 8;
  float s[8] = {0, 0, 0, 0, 0, 0, 0, 0};
#pragma unroll
  for (int zz = 0; zz < ZSLICES; ++zz) {
    uint4 v = p[t + zz * stride];
    unsigned q[4] = {v.x, v.y, v.z, v.w};
#pragma unroll
    for (int j = 0; j < 4; ++j) {
      s[2 * j]     += __uint_as_float((q[j] & 0xffffu) << 16);
      s[2 * j + 1] += __uint_as_float(q[j] & 0xffff0000u);
    }
  }
  float4 o0 = {s[0], s[1], s[2], s[3]}, o1 = {s[4], s[5], s[6], s[7]};
  ((float4*)out)[t * 2]     = o0;
  ((float4*)out)[t * 2 + 1] = o1;
}

// ---- fallback -------------------------------------------------------------------
__global__ void naive_kernel(const float* __restrict__ x, const float* __restrict__ c,
                             float* __restrict__ out) {
  __shared__ float bas[IN_DIM * NDEG];
  int b = blockIdx.x;
  for (int i = threadIdx.x; i < IN_DIM; i += 256) {
    float t = tanhf(x[(size_t)b * IN_DIM + i]);
    float L[NDEG];
    laguerre8(t, L);
#pragma unroll
    for (int d = 0; d < NDEG; ++d) bas[i * NDEG + d] = L[d];
  }
  __syncthreads();
  for (int o = threadIdx.x; o < OUT_DIM; o += 256) {
    float acc = 0.f;
    for (int i = 0; i < IN_DIM; ++i) {
      const float* cp = c + ((size_t)i * OUT_DIM + o) * NDEG;
#pragma unroll
      for (int d = 0; d < NDEG; ++d) acc += bas[i * NDEG + d] * cp[d];
    }
    out[(size_t)b * OUT_DIM + o] = acc;
  }
}

extern "C" void kernel_launch(void* const* d_in, const int* in_sizes, int n_in,
                              void* d_out, int out_size, void* d_ws, size_t ws_size,
                              hipStream_t stream) {
  const float* x    = (const float*)d_in[0];
  const float* coef = (const float*)d_in[1];
  float* out = (float*)d_out;

  const size_t A_BYTES  = (size_t)B_ROWS * KDIM * 2;              // 64 MiB
  const size_t P_BYTES  = (size_t)ZSLICES * B_ROWS * OUT_DIM * 2; // 32 MiB
  const size_t BT_BYTES = (size_t)OUT_DIM * KDIM * 2;             // 4 MiB

  if (ws_size >= A_BYTES + P_BYTES + BT_BYTES) {   // 100 MiB — proven in round 3
    unsigned short* Abuf = (unsigned short*)d_ws;
    unsigned short* Pp   = (unsigned short*)((char*)d_ws + A_BYTES);
    unsigned short* Bt   = (unsigned short*)((char*)d_ws + A_BYTES + P_BYTES);
    prep_kernel<<<(B_ROWS * IN_DIM + IN_DIM * OUT_DIM) / 256, 256, 0, stream>>>(x, coef, Abuf, Bt);
    gemm_kernel<<<512, 512, 0, stream>>>(Abuf, Bt, Pp);
    reduce_kernel<<<(B_ROWS * OUT_DIM / 8) / 256, 256, 0, stream>>>(Pp, out);
  } else {
    naive_kernel<<<B_ROWS, 256, 0, stream>>>(x, coef, out);
  }
}

// Round 5
// 67.950 us; speedup vs baseline: 1.1058x; 1.1058x over previous
//
#include <hip/hip_runtime.h>

#define B_ROWS 8192
#define IN_DIM 512
#define OUT_DIM 512
#define NDEG 8                 // DEGREE+1
#define KDIM (IN_DIM * NDEG)   // 4096
#define ZSLICES 4
#define NKT 16                 // K-tiles (of 64) per z-slice

typedef short bf16x8 __attribute__((ext_vector_type(8)));
typedef float f32x4  __attribute__((ext_vector_type(4)));

__device__ __forceinline__ unsigned short f2bf(float f) {
  unsigned u = __float_as_uint(f);
  u += 0x7fffu + ((u >> 16) & 1u);   // RNE
  return (unsigned short)(u >> 16);
}

__device__ __forceinline__ void laguerre8(float t, float* L) {
  L[0] = 1.0f;
  L[1] = 1.5f - t;
#pragma unroll
  for (int k = 2; k < NDEG; ++k)
    L[k] = ((2.0f * (float)k - 0.5f - t) * L[k - 1] -
            ((float)k - 0.5f) * L[k - 2]) * (1.0f / (float)k);
}

// Brick layout (shared by A and B): matrix of R rows x 4096 k, bf16, stored as
// 16B chunks. half-tile = 128 rows x 64 k; within half-tile h (row-block) and
// K-tile t: chunk = (h*64+t)*1024 + (rb>>6)*512 + (rb&63)*8 + (c ^ (rb&7))
// where rb = row%128, c = k-chunk 0..7. XOR pre-swizzle -> conflict-free
// ds_read_b128 after LINEAR global_load_lds staging (verified rounds 3-4).

// ---- pass 1 (merged): basis -> A bricks | coeffs -> Bt bricks -------------------
__global__ void prep_kernel(const float* __restrict__ x, const float* __restrict__ cf,
                            unsigned short* __restrict__ A, unsigned short* __restrict__ Bt) {
  int g = blockIdx.x;
  if (g < (B_ROWS * IN_DIM) / 256) {
    int idx = g * 256 + threadIdx.x;
    int b = idx >> 9, i = idx & 511;     // k = i*8 + d
    float L[NDEG];
    laguerre8(tanhf(x[idx]), L);
    uint4 v;
    v.x = (unsigned)f2bf(L[0]) | ((unsigned)f2bf(L[1]) << 16);
    v.y = (unsigned)f2bf(L[2]) | ((unsigned)f2bf(L[3]) << 16);
    v.z = (unsigned)f2bf(L[4]) | ((unsigned)f2bf(L[5]) << 16);
    v.w = (unsigned)f2bf(L[6]) | ((unsigned)f2bf(L[7]) << 16);
    int h = b >> 7, rb = b & 127, t = i >> 3, c = i & 7;
    size_t chunk = ((size_t)(h * 64 + t)) * 1024 + (rb >> 6) * 512 + (rb & 63) * 8 + (c ^ (rb & 7));
    ((uint4*)A)[chunk] = v;
  } else {
    int idx = (g - (B_ROWS * IN_DIM) / 256) * 256 + threadIdx.x;   // i*512 + o
    int i = idx >> 9, o = idx & 511;
    const float4* cp = (const float4*)(cf + (size_t)idx * 8);
    float4 c0 = cp[0], c1 = cp[1];
    uint4 v;
    v.x = (unsigned)f2bf(c0.x) | ((unsigned)f2bf(c0.y) << 16);
    v.y = (unsigned)f2bf(c0.z) | ((unsigned)f2bf(c0.w) << 16);
    v.z = (unsigned)f2bf(c1.x) | ((unsigned)f2bf(c1.y) << 16);
    v.w = (unsigned)f2bf(c1.z) | ((unsigned)f2bf(c1.w) << 16);
    int h = o >> 7, rb = o & 127, t = i >> 3, c = i & 7;
    size_t chunk = ((size_t)(h * 64 + t)) * 1024 + (rb >> 6) * 512 + (rb & 63) * 8 + (c ^ (rb & 7));
    ((uint4*)Bt)[chunk] = v;
  }
}

// ---- pass 2: GEMM 256x256 tile, counted-vmcnt raw-barrier pipeline --------------
// 8 waves (2m x 4n), wave-tile 128x64. LDS 128 KB: A/B each 2buf x 2half x 16KB.
// Per K-tile: compute(cur) | lgkm0+bar | stage(t+2 -> cur) | vmcnt(8)+bar.
__global__ __launch_bounds__(512, 2) void gemm_kernel(const unsigned short* __restrict__ A,
                                                      const unsigned short* __restrict__ Bt,
                                                      unsigned short* __restrict__ P) {
  __shared__ unsigned short lds[65536];   // 128 KB

  const int tid = threadIdx.x;
  const int lane = tid & 63;
  const int w = tid >> 6;
  const int wm = w >> 2, wn = w & 3;

  // bijective decode, A-panel sharers co-XCD: xcd = My&7
  const int g = blockIdx.x;               // 0..255
  const int j0 = g >> 3, xx = g & 7;
  const int My = ((j0 >> 3) << 3) | xx;   // 0..31
  const int n = (j0 >> 2) & 1;            // 0..1
  const int z = j0 & 3;                   // 0..3

  const uint4* Ag = (const uint4*)A;
  const uint4* Bg = (const uint4*)Bt;

  const int arow = lane & 15, hi = lane >> 4;
  const int e0 = (hi ^ (arow & 7)) * 8;   // swizzled chunk offset (shorts), ks=0

  f32x4 zero = {0.f, 0.f, 0.f, 0.f};
  f32x4 acc[8][4];
#pragma unroll
  for (int mi = 0; mi < 8; ++mi)
#pragma unroll
    for (int ni = 0; ni < 4; ++ni) acc[mi][ni] = zero;

  auto STAGE = [&](int tile, int buf) {
    const int tg = z * NKT + tile;
    const size_t cA0 = ((size_t)((My * 2 + 0) * 64 + tg)) * 1024 + w * 64 + lane;
    const size_t cA1 = ((size_t)((My * 2 + 1) * 64 + tg)) * 1024 + w * 64 + lane;
    const size_t cB0 = ((size_t)((n * 2 + 0) * 64 + tg)) * 1024 + w * 64 + lane;
    const size_t cB1 = ((size_t)((n * 2 + 1) * 64 + tg)) * 1024 + w * 64 + lane;
    unsigned short* dA = lds + buf * 16384 + w * 512;
    unsigned short* dB = lds + 32768 + buf * 16384 + w * 512;
#pragma unroll
    for (int j = 0; j < 2; ++j) {
      __builtin_amdgcn_global_load_lds(
          (const __attribute__((address_space(1))) unsigned int*)(Ag + cA0 + j * 512),
          (__attribute__((address_space(3))) unsigned int*)(dA + j * 4096), 16, 0, 0);
      __builtin_amdgcn_global_load_lds(
          (const __attribute__((address_space(1))) unsigned int*)(Ag + cA1 + j * 512),
          (__attribute__((address_space(3))) unsigned int*)(dA + 8192 + j * 4096), 16, 0, 0);
      __builtin_amdgcn_global_load_lds(
          (const __attribute__((address_space(1))) unsigned int*)(Bg + cB0 + j * 512),
          (__attribute__((address_space(3))) unsigned int*)(dB + j * 4096), 16, 0, 0);
      __builtin_amdgcn_global_load_lds(
          (const __attribute__((address_space(1))) unsigned int*)(Bg + cB1 + j * 512),
          (__attribute__((address_space(3))) unsigned int*)(dB + 8192 + j * 4096), 16, 0, 0);
    }
  };

  auto COMPUTE = [&](int buf) {
    const unsigned short* Ab = lds + buf * 16384 + wm * 8192;
    const unsigned short* Bb = lds + 32768 + buf * 16384 + (wn >> 1) * 8192 + (wn & 1) * 4096;
#pragma unroll
    for (int ks = 0; ks < 2; ++ks) {
      bf16x8 af[8], bfr[4];
#pragma unroll
      for (int mi = 0; mi < 8; ++mi)
        af[mi] = *(const bf16x8*)(Ab + (mi >> 2) * 4096 + ((mi & 3) * 16 + arow) * 64 + (e0 ^ (ks * 32)));
#pragma unroll
      for (int ni = 0; ni < 4; ++ni)
        bfr[ni] = *(const bf16x8*)(Bb + (ni * 16 + arow) * 64 + (e0 ^ (ks * 32)));
      __builtin_amdgcn_s_setprio(1);
#pragma unroll
      for (int mi = 0; mi < 8; ++mi)
#pragma unroll
        for (int ni = 0; ni < 4; ++ni)
          acc[mi][ni] = __builtin_amdgcn_mfma_f32_16x16x32_bf16(af[mi], bfr[ni], acc[mi][ni], 0, 0, 0);
      __builtin_amdgcn_s_setprio(0);
    }
  };

  // ---- prologue: tiles 0,1 in flight ----
  STAGE(0, 0);
  STAGE(1, 1);
  asm volatile("s_waitcnt vmcnt(8)" ::: "memory");   // tile 0 landed
  __builtin_amdgcn_sched_barrier(0);
  __builtin_amdgcn_s_barrier();

  // ---- main loop: t = 0..13 ----
  for (int t = 0; t < NKT - 2; ++t) {
    const int cur = t & 1;
    COMPUTE(cur);
    asm volatile("s_waitcnt lgkmcnt(0)" ::: "memory");   // my reads of buf[cur] done
    __builtin_amdgcn_sched_barrier(0);
    __builtin_amdgcn_s_barrier();                        // all waves done reading
    STAGE(t + 2, cur);                                   // overwrite with t+2
    asm volatile("s_waitcnt vmcnt(8)" ::: "memory");     // t+1 landed (t+2 in flight)
    __builtin_amdgcn_sched_barrier(0);
    __builtin_amdgcn_s_barrier();
  }
  // ---- peel t=14, t=15 ----
  COMPUTE(0);
  asm volatile("s_waitcnt vmcnt(0)" ::: "memory");       // tile 15 landed
  __builtin_amdgcn_sched_barrier(0);
  __builtin_amdgcn_s_barrier();
  COMPUTE(1);
  __syncthreads();   // safe: no vmem outstanding; lgkm drained by data deps

  // ---- epilogue: bf16 via per-wave LDS bounce (swizzled) -> uint4 line stores ----
  unsigned short* W = lds + w * 8192;    // 128 rows x 64 shorts per wave
#pragma unroll
  for (int mi = 0; mi < 8; ++mi)
#pragma unroll
    for (int ni = 0; ni < 4; ++ni) {
      int col = ni * 16 + arow;
      int c8 = col >> 3, cpos = col & 7;
#pragma unroll
      for (int r = 0; r < 4; ++r) {
        int row = mi * 16 + hi * 4 + r;
        W[row * 64 + ((c8 ^ (row & 7)) << 3) + cpos] = f2bf(acc[mi][ni][r]);
      }
    }
  const int rr = lane >> 3, cc = lane & 7;
#pragma unroll
  for (int it = 0; it < 16; ++it) {
    int row = it * 8 + rr;
    uint4 v = *(uint4*)&W[row * 64 + ((cc ^ (row & 7)) << 3)];
    size_t pr = ((size_t)z * B_ROWS + My * 256 + wm * 128 + row) * 512 + n * 256 + wn * 64 + cc * 8;
    *(uint4*)&P[pr] = v;
  }
}

// ---- pass 3: out = sum of bf16 partials, f32 ------------------------------------
__global__ void reduce_kernel(const unsigned short* __restrict__ P, float* __restrict__ out) {
  size_t t = (size_t)blockIdx.x * 256 + threadIdx.x;
  const uint4* p = (const uint4*)P;
  const size_t stride = (size_t)B_ROWS * OUT_DIM / 8;
  float s[8] = {0, 0, 0, 0, 0, 0, 0, 0};
#pragma unroll
  for (int zz = 0; zz < ZSLICES; ++zz) {
    uint4 v = p[t + zz * stride];
    unsigned q[4] = {v.x, v.y, v.z, v.w};
#pragma unroll
    for (int j = 0; j < 4; ++j) {
      s[2 * j]     += __uint_as_float((q[j] & 0xffffu) << 16);
      s[2 * j + 1] += __uint_as_float(q[j] & 0xffff0000u);
    }
  }
  float4 o0 = {s[0], s[1], s[2], s[3]}, o1 = {s[4], s[5], s[6], s[7]};
  ((float4*)out)[t * 2]     = o0;
  ((float4*)out)[t * 2 + 1] = o1;
}

// ---- fallback -------------------------------------------------------------------
__global__ void naive_kernel(const float* __restrict__ x, const float* __restrict__ c,
                             float* __restrict__ out) {
  __shared__ float bas[IN_DIM * NDEG];
  int b = blockIdx.x;
  for (int i = threadIdx.x; i < IN_DIM; i += 256) {
    float t = tanhf(x[(size_t)b * IN_DIM + i]);
    float L[NDEG];
    laguerre8(t, L);
#pragma unroll
    for (int d = 0; d < NDEG; ++d) bas[i * NDEG + d] = L[d];
  }
  __syncthreads();
  for (int o = threadIdx.x; o < OUT_DIM; o += 256) {
    float acc = 0.f;
    for (int i = 0; i < IN_DIM; ++i) {
      const float* cp = c + ((size_t)i * OUT_DIM + o) * NDEG;
#pragma unroll
      for (int d = 0; d < NDEG; ++d) acc += bas[i * NDEG + d] * cp[d];
    }
    out[(size_t)b * OUT_DIM + o] = acc;
  }
}

extern "C" void kernel_launch(void* const* d_in, const int* in_sizes, int n_in,
                              void* d_out, int out_size, void* d_ws, size_t ws_size,
                              hipStream_t stream) {
  const float* x    = (const float*)d_in[0];
  const float* coef = (const float*)d_in[1];
  float* out = (float*)d_out;

  const size_t A_BYTES  = (size_t)B_ROWS * KDIM * 2;              // 64 MiB
  const size_t P_BYTES  = (size_t)ZSLICES * B_ROWS * OUT_DIM * 2; // 32 MiB
  const size_t BT_BYTES = (size_t)OUT_DIM * KDIM * 2;             // 4 MiB

  if (ws_size >= A_BYTES + P_BYTES + BT_BYTES) {   // 100 MiB — proven in rounds 3-4
    unsigned short* Abuf = (unsigned short*)d_ws;
    unsigned short* Pp   = (unsigned short*)((char*)d_ws + A_BYTES);
    unsigned short* Bt   = (unsigned short*)((char*)d_ws + A_BYTES + P_BYTES);
    prep_kernel<<<(B_ROWS * IN_DIM + IN_DIM * OUT_DIM) / 256, 256, 0, stream>>>(x, coef, Abuf, Bt);
    gemm_kernel<<<256, 512, 0, stream>>>(Abuf, Bt, Pp);
    reduce_kernel<<<(B_ROWS * OUT_DIM / 8) / 256, 256, 0, stream>>>(Pp, out);
  } else {
    naive_kernel<<<B_ROWS, 256, 0, stream>>>(x, coef, out);
  }
}

// Round 6
// 67.102 us; speedup vs baseline: 1.1198x; 1.0126x over previous
//
#include <hip/hip_runtime.h>

#define B_ROWS 8192
#define IN_DIM 512
#define OUT_DIM 512
#define NDEG 8                 // DEGREE+1
#define KDIM (IN_DIM * NDEG)   // 4096
#define ZSLICES 4
#define NKT 16                 // K-tiles (of 64) per z-slice

typedef short bf16x8 __attribute__((ext_vector_type(8)));
typedef float f32x4  __attribute__((ext_vector_type(4)));

__device__ __forceinline__ unsigned short f2bf(float f) {
  unsigned u = __float_as_uint(f);
  u += 0x7fffu + ((u >> 16) & 1u);   // RNE
  return (unsigned short)(u >> 16);
}

__device__ __forceinline__ void laguerre8(float t, float* L) {
  L[0] = 1.0f;
  L[1] = 1.5f - t;
#pragma unroll
  for (int k = 2; k < NDEG; ++k)
    L[k] = ((2.0f * (float)k - 0.5f - t) * L[k - 1] -
            ((float)k - 0.5f) * L[k - 2]) * (1.0f / (float)k);
}

// Brick layout (A and B identical): R rows x 4096 k bf16 as 16B chunks.
// half-tile = 128 rows x 64 k; chunk = (rowblk*64 + ktile)*1024
//   + (rb>>6)*512 + (rb&63)*8 + (c ^ (rb&7)),  rb=row%128, c=kchunk 0..7.
// XOR pre-swizzle -> conflict-free ds_read_b128 after LINEAR gl_lds staging
// (verified: SQ_LDS_BANK_CONFLICT == 0 in round 5).

// ---- pass 1 (merged): basis -> A bricks | coeffs -> Bt bricks -------------------
__global__ void prep_kernel(const float* __restrict__ x, const float* __restrict__ cf,
                            unsigned short* __restrict__ A, unsigned short* __restrict__ Bt) {
  int g = blockIdx.x;
  if (g < (B_ROWS * IN_DIM) / 256) {
    int idx = g * 256 + threadIdx.x;
    int b = idx >> 9, i = idx & 511;     // k = i*8 + d
    float L[NDEG];
    laguerre8(tanhf(x[idx]), L);
    uint4 v;
    v.x = (unsigned)f2bf(L[0]) | ((unsigned)f2bf(L[1]) << 16);
    v.y = (unsigned)f2bf(L[2]) | ((unsigned)f2bf(L[3]) << 16);
    v.z = (unsigned)f2bf(L[4]) | ((unsigned)f2bf(L[5]) << 16);
    v.w = (unsigned)f2bf(L[6]) | ((unsigned)f2bf(L[7]) << 16);
    int h = b >> 7, rb = b & 127, t = i >> 3, c = i & 7;
    size_t chunk = ((size_t)(h * 64 + t)) * 1024 + (rb >> 6) * 512 + (rb & 63) * 8 + (c ^ (rb & 7));
    ((uint4*)A)[chunk] = v;
  } else {
    int idx = (g - (B_ROWS * IN_DIM) / 256) * 256 + threadIdx.x;   // i*512 + o
    int i = idx >> 9, o = idx & 511;
    const float4* cp = (const float4*)(cf + (size_t)idx * 8);
    float4 c0 = cp[0], c1 = cp[1];
    uint4 v;
    v.x = (unsigned)f2bf(c0.x) | ((unsigned)f2bf(c0.y) << 16);
    v.y = (unsigned)f2bf(c0.z) | ((unsigned)f2bf(c0.w) << 16);
    v.z = (unsigned)f2bf(c1.x) | ((unsigned)f2bf(c1.y) << 16);
    v.w = (unsigned)f2bf(c1.z) | ((unsigned)f2bf(c1.w) << 16);
    int h = o >> 7, rb = o & 127, t = i >> 3, c = i & 7;
    size_t chunk = ((size_t)(h * 64 + t)) * 1024 + (rb >> 6) * 512 + (rb & 63) * 8 + (c ^ (rb & 7));
    ((uint4*)Bt)[chunk] = v;
  }
}

// ---- pass 2: GEMM 256x256, 8-phase m201 schedule --------------------------------
// 8 waves (2m x 4n), wave-tile 128x64, acc[8][4]. LDS 128 KB, 2-buf ring.
// Phase = {4/8 ds_read, 1 half-tile gl_lds stage, bar, lgkm0, 16 MFMA, bar};
// vmcnt(2) only at phases 3/7 (counted — loads stay in flight across barriers).

#define PH(buf, mq, ks, LOADBF, VMW, ...)                                          \
  {                                                                                \
    const unsigned short* Ab_ = lds + (buf)*16384 + wm*8192 + (mq)*4096 + arow*64; \
    _Pragma("unroll") for (int m4 = 0; m4 < 4; ++m4)                               \
      af[m4] = *(const bf16x8*)(Ab_ + m4*1024 + (e ^ ((ks)*32)));                  \
    if (LOADBF) {                                                                  \
      const unsigned short* Bb_ = lds + 32768 + (buf)*16384 + (wn>>1)*8192         \
                                  + (wn&1)*4096 + arow*64;                         \
      _Pragma("unroll") for (int ni = 0; ni < 4; ++ni)                             \
        bfr[ni] = *(const bf16x8*)(Bb_ + ni*1024 + (e ^ ((ks)*32)));               \
    }                                                                              \
    __VA_ARGS__;                                                                   \
    __builtin_amdgcn_s_barrier();                                                  \
    asm volatile("s_waitcnt lgkmcnt(0)" ::: "memory");                             \
    __builtin_amdgcn_sched_barrier(0);                                             \
    __builtin_amdgcn_s_setprio(1);                                                 \
    _Pragma("unroll") for (int m4 = 0; m4 < 4; ++m4)                               \
      _Pragma("unroll") for (int ni = 0; ni < 4; ++ni)                             \
        acc[(mq)*4+m4][ni] = __builtin_amdgcn_mfma_f32_16x16x32_bf16(              \
            af[m4], bfr[ni], acc[(mq)*4+m4][ni], 0, 0, 0);                         \
    __builtin_amdgcn_s_setprio(0);                                                 \
    if ((VMW) == 1) { asm volatile("s_waitcnt vmcnt(2)" ::: "memory");             \
                      __builtin_amdgcn_sched_barrier(0); }                         \
    if ((VMW) == 2) { asm volatile("s_waitcnt vmcnt(0)" ::: "memory");             \
                      __builtin_amdgcn_sched_barrier(0); }                         \
    __builtin_amdgcn_s_barrier();                                                  \
  }

__global__ __launch_bounds__(512, 2) void gemm_kernel(const unsigned short* __restrict__ A,
                                                      const unsigned short* __restrict__ Bt,
                                                      unsigned short* __restrict__ P) {
  __shared__ unsigned short lds[65536];   // 128 KB: A ring 64 KB | B ring 64 KB

  const int tid = threadIdx.x;
  const int lane = tid & 63;
  const int w = tid >> 6;
  const int wm = w >> 2, wn = w & 3;

  // bijective decode, A-panel sharers co-XCD
  const int g = blockIdx.x;               // 0..255
  const int j0 = g >> 3, xx = g & 7;
  const int My = ((j0 >> 3) << 3) | xx;   // 0..31
  const int n = (j0 >> 2) & 1;            // 0..1
  const int z = j0 & 3;                   // 0..3

  const uint4* Ag = (const uint4*)A;
  const uint4* Bg = (const uint4*)Bt;

  const int arow = lane & 15, hi = lane >> 4;
  const int e = (hi ^ (arow & 7)) * 8;    // swizzled chunk offset (shorts)

  f32x4 zero = {0.f, 0.f, 0.f, 0.f};
  f32x4 acc[8][4];
#pragma unroll
  for (int mi = 0; mi < 8; ++mi)
#pragma unroll
    for (int ni = 0; ni < 4; ++ni) acc[mi][ni] = zero;

  // stage one 16KB half-tile: 2 gl_lds per wave (linear chunk->chunk)
  auto STAGE_H = [&](int isB, int h, int tile, int buf) {
    const uint4* src = isB ? Bg : Ag;
    const int rowblk = (isB ? n * 2 : My * 2) + h;
    const size_t c0 = ((size_t)(rowblk * 64 + z * NKT + tile)) * 1024 + w * 64 + lane;
    unsigned short* d = lds + isB * 32768 + buf * 16384 + h * 8192 + w * 512;
    __builtin_amdgcn_global_load_lds(
        (const __attribute__((address_space(1))) unsigned int*)(src + c0),
        (__attribute__((address_space(3))) unsigned int*)d, 16, 0, 0);
    __builtin_amdgcn_global_load_lds(
        (const __attribute__((address_space(1))) unsigned int*)(src + c0 + 512),
        (__attribute__((address_space(3))) unsigned int*)(d + 4096), 16, 0, 0);
  };

  bf16x8 af[4], bfr[4];

  // ---- prologue: tile0 (4 halves) -> buf0, B0(tile1) -> buf1; 10 loads ----
  STAGE_H(0, 0, 0, 0); STAGE_H(0, 1, 0, 0);
  STAGE_H(1, 0, 0, 0); STAGE_H(1, 1, 0, 0);
  STAGE_H(1, 0, 1, 1);
  asm volatile("s_waitcnt vmcnt(2)" ::: "memory");   // tile0 landed; B0(t1) in flight
  __builtin_amdgcn_sched_barrier(0);
  __builtin_amdgcn_s_barrier();

  // ---- main loop: iters 0..6, tiles (2it, 2it+1); stage t1-rest, t2, B0(t3) ----
  for (int it = 0; it < 7; ++it) {
    const int t1 = 2 * it + 1, t2 = 2 * it + 2, t3 = 2 * it + 3;
    PH(0, 0, 0, 1, 0, STAGE_H(1, 1, t1, 1));   // p0: +bf(ks0); stage B1(t1)
    PH(0, 1, 0, 0, 0, STAGE_H(0, 0, t1, 1));   // p1: stage A0(t1)
    PH(0, 0, 1, 1, 0, STAGE_H(0, 1, t1, 1));   // p2: +bf(ks1); stage A1(t1)
    PH(0, 1, 1, 0, 1, STAGE_H(1, 0, t2, 0));   // p3: stage B0(t2); vmcnt(2)
    PH(1, 0, 0, 1, 0, STAGE_H(0, 0, t2, 0));   // p4: stage A0(t2)
    PH(1, 1, 0, 0, 0, STAGE_H(0, 1, t2, 0));   // p5: stage A1(t2)
    PH(1, 0, 1, 1, 0, STAGE_H(1, 1, t2, 0));   // p6: stage B1(t2)
    PH(1, 1, 1, 0, 1, STAGE_H(1, 0, t3, 1));   // p7: stage B0(t3); vmcnt(2)
  }
  // ---- peeled iter 7: tiles 14,15; finish staging t1=15, no further stages ----
  PH(0, 0, 0, 1, 0, STAGE_H(1, 1, 15, 1));
  PH(0, 1, 0, 0, 0, STAGE_H(0, 0, 15, 1));
  PH(0, 0, 1, 1, 0, STAGE_H(0, 1, 15, 1));
  PH(0, 1, 1, 0, 2, (void)0);                  // vmcnt(0): tile15 fully landed
  PH(1, 0, 0, 1, 0, (void)0);
  PH(1, 1, 0, 0, 0, (void)0);
  PH(1, 0, 1, 1, 0, (void)0);
  PH(1, 1, 1, 0, 0, (void)0);

  // ---- epilogue: bf16 via per-wave LDS bounce (swizzled) -> uint4 line stores ----
  unsigned short* W = lds + w * 8192;    // 128 rows x 64 shorts per wave
#pragma unroll
  for (int mi = 0; mi < 8; ++mi)
#pragma unroll
    for (int ni = 0; ni < 4; ++ni) {
      int col = ni * 16 + arow;
      int c8 = col >> 3, cpos = col & 7;
#pragma unroll
      for (int r = 0; r < 4; ++r) {
        int row = mi * 16 + hi * 4 + r;
        W[row * 64 + ((c8 ^ (row & 7)) << 3) + cpos] = f2bf(acc[mi][ni][r]);
      }
    }
  const int rr = lane >> 3, cc = lane & 7;
#pragma unroll
  for (int it = 0; it < 16; ++it) {
    int row = it * 8 + rr;
    uint4 v = *(uint4*)&W[row * 64 + ((cc ^ (row & 7)) << 3)];
    size_t pr = ((size_t)z * B_ROWS + My * 256 + wm * 128 + row) * 512 + n * 256 + wn * 64 + cc * 8;
    *(uint4*)&P[pr] = v;
  }
}

// ---- pass 3: out = sum of bf16 partials, f32 ------------------------------------
__global__ void reduce_kernel(const unsigned short* __restrict__ P, float* __restrict__ out) {
  size_t t = (size_t)blockIdx.x * 256 + threadIdx.x;
  const uint4* p = (const uint4*)P;
  const size_t stride = (size_t)B_ROWS * OUT_DIM / 8;
  float s[8] = {0, 0, 0, 0, 0, 0, 0, 0};
#pragma unroll
  for (int zz = 0; zz < ZSLICES; ++zz) {
    uint4 v = p[t + zz * stride];
    unsigned q[4] = {v.x, v.y, v.z, v.w};
#pragma unroll
    for (int j = 0; j < 4; ++j) {
      s[2 * j]     += __uint_as_float((q[j] & 0xffffu) << 16);
      s[2 * j + 1] += __uint_as_float(q[j] & 0xffff0000u);
    }
  }
  float4 o0 = {s[0], s[1], s[2], s[3]}, o1 = {s[4], s[5], s[6], s[7]};
  ((float4*)out)[t * 2]     = o0;
  ((float4*)out)[t * 2 + 1] = o1;
}

// ---- fallback -------------------------------------------------------------------
__global__ void naive_kernel(const float* __restrict__ x, const float* __restrict__ c,
                             float* __restrict__ out) {
  __shared__ float bas[IN_DIM * NDEG];
  int b = blockIdx.x;
  for (int i = threadIdx.x; i < IN_DIM; i += 256) {
    float t = tanhf(x[(size_t)b * IN_DIM + i]);
    float L[NDEG];
    laguerre8(t, L);
#pragma unroll
    for (int d = 0; d < NDEG; ++d) bas[i * NDEG + d] = L[d];
  }
  __syncthreads();
  for (int o = threadIdx.x; o < OUT_DIM; o += 256) {
    float acc = 0.f;
    for (int i = 0; i < IN_DIM; ++i) {
      const float* cp = c + ((size_t)i * OUT_DIM + o) * NDEG;
#pragma unroll
      for (int d = 0; d < NDEG; ++d) acc += bas[i * NDEG + d] * cp[d];
    }
    out[(size_t)b * OUT_DIM + o] = acc;
  }
}

extern "C" void kernel_launch(void* const* d_in, const int* in_sizes, int n_in,
                              void* d_out, int out_size, void* d_ws, size_t ws_size,
                              hipStream_t stream) {
  const float* x    = (const float*)d_in[0];
  const float* coef = (const float*)d_in[1];
  float* out = (float*)d_out;

  const size_t A_BYTES  = (size_t)B_ROWS * KDIM * 2;              // 64 MiB
  const size_t P_BYTES  = (size_t)ZSLICES * B_ROWS * OUT_DIM * 2; // 32 MiB
  const size_t BT_BYTES = (size_t)OUT_DIM * KDIM * 2;             // 4 MiB

  if (ws_size >= A_BYTES + P_BYTES + BT_BYTES) {   // 100 MiB — proven rounds 3-5
    unsigned short* Abuf = (unsigned short*)d_ws;
    unsigned short* Pp   = (unsigned short*)((char*)d_ws + A_BYTES);
    unsigned short* Bt   = (unsigned short*)((char*)d_ws + A_BYTES + P_BYTES);
    prep_kernel<<<(B_ROWS * IN_DIM + IN_DIM * OUT_DIM) / 256, 256, 0, stream>>>(x, coef, Abuf, Bt);
    gemm_kernel<<<256, 512, 0, stream>>>(Abuf, Bt, Pp);
    reduce_kernel<<<(B_ROWS * OUT_DIM / 8) / 256, 256, 0, stream>>>(Pp, out);
  } else {
    naive_kernel<<<B_ROWS, 256, 0, stream>>>(x, coef, out);
  }
}